// Round 1
// baseline (229.893 us; speedup 1.0000x reference)
//
#include <hip/hip_runtime.h>
#include <hip/hip_bf16.h>
#include <cstdint>

#define B_ 32
#define D_ 256
#define H_ 32
#define W_ 32
#define K_ 1024
#define N_TOK (B_ * H_ * W_)        // 32768 tokens
#define Z_ELEMS (B_ * D_ * H_ * W_) // 8388608
#define OUT_IDX_OFF Z_ELEMS
#define OUT_LOSS_OFF (Z_ELEMS + N_TOK)

// ws layout:
//   [0, 262144)        u64 keys[32768]   (packed d2|idx, atomicMin target)
//   [262144, 266240)   f32 cnorm[1024]
//   [266240, 270336)   f32 partials[1024]
#define WS_CNORM_OFF 262144
#define WS_PART_OFF  266240

// ---------------- kernel 0: codebook row norms ----------------
__global__ __launch_bounds__(256) void cnorm_kernel(const float* __restrict__ cb,
                                                    float* __restrict__ cnorm) {
    int t = threadIdx.x;
    int k = blockIdx.x * 64 + (t >> 2);
    int part = t & 3;
    const float4* row = reinterpret_cast<const float4*>(cb + k * D_);
    float s = 0.f;
#pragma unroll
    for (int j = 0; j < 16; ++j) {
        float4 v = row[part * 16 + j];
        s += v.x * v.x + v.y * v.y + v.z * v.z + v.w * v.w;
    }
    s += __shfl_xor(s, 1);
    s += __shfl_xor(s, 2);
    if (part == 0) cnorm[k] = s;
}

// ---------------- kernel 1: fused distance GEMM + argmin ----------------
// block tile: 128 tokens x 128 codes, DK=8, 256 threads, per-thread 8x8 (split 4+4)
#define TM 128
#define TN 128
#define DK 8
#define LDSTR 132  // padded LDS row stride (floats), 16B-aligned rows

__global__ __launch_bounds__(256, 3)
void dist_kernel(const float* __restrict__ z, const float* __restrict__ cb,
                 const float* __restrict__ cnorm,
                 unsigned long long* __restrict__ keys) {
    __shared__ float zs[DK][LDSTR];
    __shared__ float cs[DK][LDSTR];
    __shared__ float cns[TN];

    const int tid = threadIdx.x;
    const int blk = blockIdx.x;
    const int ttile = blk >> 3;  // 0..255
    const int ctile = blk & 7;   // 0..7
    const int token0 = ttile * TM;
    const int b = token0 >> 10;
    const int hw0 = token0 & 1023;
    const int k0 = ctile * TN;

    const float* zb = z + (size_t)b * (D_ * H_ * W_) + hw0; // + d*1024 + m
    const float* cbb = cb + (size_t)k0 * D_;                // + k*256 + d

    if (tid < 32) {
        float4 v = reinterpret_cast<const float4*>(cnorm + k0)[tid];
        cns[tid * 4 + 0] = v.x; cns[tid * 4 + 1] = v.y;
        cns[tid * 4 + 2] = v.z; cns[tid * 4 + 3] = v.w;
    }

    float acc[2][4][2][4];
#pragma unroll
    for (int a = 0; a < 2; ++a)
#pragma unroll
        for (int i = 0; i < 4; ++i)
#pragma unroll
            for (int c = 0; c < 2; ++c)
#pragma unroll
                for (int j = 0; j < 4; ++j) acc[a][i][c][j] = 0.f;

    const int tx = tid & 15;   // code group
    const int ty = tid >> 4;   // token group

    const int zm = (tid & 31) * 4;  // token quad base for staging
    const int zd = tid >> 5;        // 0..7 d-row for staging
    const int ck = tid >> 1;        // 0..127 code row for staging
    const int cd4 = (tid & 1) * 4;  // 0 or 4

    for (int d0 = 0; d0 < D_; d0 += DK) {
        float4 zv = *reinterpret_cast<const float4*>(zb + (d0 + zd) * 1024 + zm);
        float4 cv = *reinterpret_cast<const float4*>(cbb + ck * D_ + d0 + cd4);
        __syncthreads();  // previous compute done before overwriting LDS
        *reinterpret_cast<float4*>(&zs[zd][zm]) = zv;
        cs[cd4 + 0][ck] = cv.x;
        cs[cd4 + 1][ck] = cv.y;
        cs[cd4 + 2][ck] = cv.z;
        cs[cd4 + 3][ck] = cv.w;
        __syncthreads();
#pragma unroll
        for (int d = 0; d < DK; ++d) {
            float4 za0 = *reinterpret_cast<const float4*>(&zs[d][ty * 4]);
            float4 za1 = *reinterpret_cast<const float4*>(&zs[d][64 + ty * 4]);
            float4 ca0 = *reinterpret_cast<const float4*>(&cs[d][tx * 4]);
            float4 ca1 = *reinterpret_cast<const float4*>(&cs[d][64 + tx * 4]);
            const float za[2][4] = {{za0.x, za0.y, za0.z, za0.w},
                                    {za1.x, za1.y, za1.z, za1.w}};
            const float ca[2][4] = {{ca0.x, ca0.y, ca0.z, ca0.w},
                                    {ca1.x, ca1.y, ca1.z, ca1.w}};
#pragma unroll
            for (int a = 0; a < 2; ++a)
#pragma unroll
                for (int i = 0; i < 4; ++i)
#pragma unroll
                    for (int c = 0; c < 2; ++c)
#pragma unroll
                        for (int j = 0; j < 4; ++j)
                            acc[a][i][c][j] = fmaf(za[a][i], ca[c][j], acc[a][i][c][j]);
        }
    }

    // epilogue: per-token argmin over this block's 128 codes, then global atomicMin
#pragma unroll
    for (int a = 0; a < 2; ++a) {
#pragma unroll
        for (int i = 0; i < 4; ++i) {
            const int tok = a * 64 + ty * 4 + i;
            float best = 3.4e38f;
            int bestk = 0;
#pragma unroll
            for (int c = 0; c < 2; ++c) {
#pragma unroll
                for (int j = 0; j < 4; ++j) {
                    const int kk = c * 64 + tx * 4 + j;  // ascending order
                    const float d2 = cns[kk] - 2.f * acc[a][i][c][j];
                    if (d2 < best) { best = d2; bestk = kk; }
                }
            }
            unsigned int ub = __float_as_uint(best);
            ub = (ub & 0x80000000u) ? ~ub : (ub | 0x80000000u);
            unsigned long long key =
                ((unsigned long long)ub << 32) | (unsigned long long)(k0 + bestk);
#pragma unroll
            for (int m = 1; m < 16; m <<= 1) {
                unsigned long long o = __shfl_xor(key, m);
                if (o < key) key = o;
            }
            if (tx == 0) atomicMin(&keys[token0 + tok], key);
        }
    }
}

// ---------------- kernel 2: gather + transpose write + idx + loss partials ----------------
__global__ __launch_bounds__(256)
void gather_kernel(const float* __restrict__ z, const float* __restrict__ cb,
                   const unsigned long long* __restrict__ keys,
                   float* __restrict__ out, float* __restrict__ partials) {
    __shared__ int sidx[32];
    __shared__ float crows[32][257];
    __shared__ float red[256];
    const int t = threadIdx.x;
    const int bh = blockIdx.x;  // 0..1023
    const int b = bh >> 5, h = bh & 31;
    const int n0 = b * 1024 + h * 32;

    if (t < 32) {
        unsigned long long key = keys[n0 + t];
        int k = (int)(key & 0xffffffffull);
        sidx[t] = k;
        out[OUT_IDX_OFF + n0 + t] = (float)k;
    }
    __syncthreads();
    {
        const int r = t >> 3, seg = t & 7;
        const float4* src = reinterpret_cast<const float4*>(cb + (size_t)sidx[r] * D_ + seg * 32);
#pragma unroll
        for (int j = 0; j < 8; ++j) {
            float4 v = src[j];
            int d = seg * 32 + j * 4;
            crows[r][d] = v.x; crows[r][d + 1] = v.y;
            crows[r][d + 2] = v.z; crows[r][d + 3] = v.w;
        }
    }
    __syncthreads();
    const int w = t & 31, dg = t >> 5;
    const float* zrow = z + (size_t)b * (D_ * H_ * W_) + h * 32 + w;
    float* orow = out + (size_t)b * (D_ * H_ * W_) + h * 32 + w;
    float accl = 0.f;
#pragma unroll
    for (int i = 0; i < 32; ++i) {
        const int d = dg * 32 + i;
        const float cv = crows[w][d];
        const float zv = zrow[d * 1024];
        orow[d * 1024] = cv;
        const float df = cv - zv;
        accl += df * df;
    }
    red[t] = accl;
    __syncthreads();
    for (int s = 128; s > 0; s >>= 1) {
        if (t < s) red[t] += red[t + s];
        __syncthreads();
    }
    if (t == 0) partials[bh] = red[0];
}

// ---------------- kernel 3: deterministic final loss reduction ----------------
__global__ __launch_bounds__(256) void loss_kernel(const float* __restrict__ partials,
                                                   float* __restrict__ out) {
    __shared__ float red[256];
    const int t = threadIdx.x;
    float s = partials[t] + partials[t + 256] + partials[t + 512] + partials[t + 768];
    red[t] = s;
    __syncthreads();
    for (int st = 128; st > 0; st >>= 1) {
        if (t < st) red[t] += red[t + st];
        __syncthreads();
    }
    if (t == 0) out[OUT_LOSS_OFF] = red[0] * (1.25f / (float)Z_ELEMS);
}

extern "C" void kernel_launch(void* const* d_in, const int* in_sizes, int n_in,
                              void* d_out, int out_size, void* d_ws, size_t ws_size,
                              hipStream_t stream) {
    const float* z = (const float*)d_in[0];   // [32,256,32,32] f32
    const float* cb = (const float*)d_in[1];  // [1024,256] f32
    float* out = (float*)d_out;
    unsigned long long* keys = (unsigned long long*)d_ws;
    float* cnorm = (float*)((char*)d_ws + WS_CNORM_OFF);
    float* partials = (float*)((char*)d_ws + WS_PART_OFF);

    // init argmin keys to max
    hipMemsetAsync(d_ws, 0xFF, 262144, stream);

    cnorm_kernel<<<16, 256, 0, stream>>>(cb, cnorm);
    dist_kernel<<<2048, 256, 0, stream>>>(z, cb, cnorm, keys);
    gather_kernel<<<1024, 256, 0, stream>>>(z, cb, keys, out, partials);
    loss_kernel<<<1, 256, 0, stream>>>(partials, out);
}

// Round 2
// 96.749 us; speedup vs baseline: 2.3762x; 2.3762x over previous
//
#include <hip/hip_runtime.h>
#include <hip/hip_bf16.h>
#include <cstdint>

#define B_ 32
#define D_ 256
#define K_ 1024
#define N_TOK 32768
#define Z_ELEMS 8388608
#define OUT_IDX_OFF Z_ELEMS
#define OUT_LOSS_OFF (Z_ELEMS + N_TOK)

// ws layout:
//   [0,4096)           f32 cnorm[1024]
//   [4096,8192)        f32 partials[1024]
//   [8192,270336)      u64 keys[32768]          (final idx, low 32 bits)
//   [270336,4464640)   u64 top2[32768][8][2]    (screen per-block top-2 keys)
#define WS_CNORM_OFF 0
#define WS_PART_OFF  4096
#define WS_KEYS_OFF  8192
#define WS_TOP2_OFF  270336

#define MARGIN 1.0f

typedef __attribute__((ext_vector_type(8))) short short8v;
typedef __attribute__((ext_vector_type(4))) float f32x4;
typedef unsigned long long u64;

__device__ __forceinline__ unsigned short f2bf(float x) {
    unsigned u = __float_as_uint(x);
    return (unsigned short)((u + 0x7fffu + ((u >> 16) & 1u)) >> 16);  // RNE
}
__device__ __forceinline__ unsigned packf(float f) {
    unsigned u = __float_as_uint(f);
    return (u & 0x80000000u) ? ~u : (u | 0x80000000u);  // order-preserving bits
}
__device__ __forceinline__ float unpackf(unsigned p) {
    unsigned u = (p & 0x80000000u) ? (p & 0x7fffffffu) : ~p;
    return __uint_as_float(u);
}

// ---------------- kernel 0: codebook row norms (fp32, exact) ----------------
__global__ __launch_bounds__(256) void cnorm_kernel(const float* __restrict__ cb,
                                                    float* __restrict__ cnorm) {
    int t = threadIdx.x;
    int k = blockIdx.x * 64 + (t >> 2);
    int part = t & 3;
    const float4* row = reinterpret_cast<const float4*>(cb + k * D_);
    float s = 0.f;
#pragma unroll
    for (int j = 0; j < 16; ++j) {
        float4 v = row[part * 16 + j];
        s += v.x * v.x + v.y * v.y + v.z * v.z + v.w * v.w;
    }
    s += __shfl_xor(s, 1);
    s += __shfl_xor(s, 2);
    if (part == 0) cnorm[k] = s;
}

// ---------------- kernel 1: bf16 MFMA screen + per-block top-2 ----------------
// block: 128 tokens x 128 codes, 256 thr (4 waves), wave = 128 codes x 32 tokens
__global__ __launch_bounds__(256, 2)
void screen_kernel(const float* __restrict__ z, const float* __restrict__ cb,
                   const float* __restrict__ cnorm, u64* __restrict__ top2) {
    __shared__ __align__(16) unsigned char AsB[8192];  // [code 128][k 32] bf16, XOR-swizzled
    __shared__ __align__(16) unsigned char BsB[8192];  // [tok 128][k 32] bf16, XOR-swizzled
    __shared__ float cns[128];

    const int t = threadIdx.x;
    const int lane = t & 63;
    const int wave = t >> 6;
    const int blk = blockIdx.x;
    const int ttile = blk >> 3;   // 0..255
    const int cblk = blk & 7;     // 0..7
    const int b = ttile >> 3;
    const int hw0 = (ttile & 7) << 7;

    const float* zb = z + (size_t)b * 262144 + hw0;       // + d*1024 + tok
    const float* cbt = cb + (size_t)cblk * 128 * 256;     // + code*256 + d

    if (t < 128) cns[t] = cnorm[cblk * 128 + t];

    f32x4 acc[8][2];
#pragma unroll
    for (int mt = 0; mt < 8; ++mt)
#pragma unroll
        for (int nt = 0; nt < 2; ++nt) acc[mt][nt] = (f32x4){0.f, 0.f, 0.f, 0.f};

    const int btok = t & 127, bkh = t >> 7;

    for (int ks = 0; ks < 8; ++ks) {
        // ---- issue global loads (coalesced) ----
        float2 av[8];
#pragma unroll
        for (int i = 0; i < 8; ++i) {
            int p = i * 512 + t * 2;          // flat (code,k) of A tile
            int code = p >> 5, kk = p & 31;   // kk even
            av[i] = *(const float2*)(cbt + code * 256 + ks * 32 + kk);
        }
        float bv[16];
#pragma unroll
        for (int j = 0; j < 16; ++j)
            bv[j] = zb[(size_t)(ks * 32 + bkh * 16 + j) * 1024 + btok];

        __syncthreads();  // previous MFMA frag reads done

        // ---- cvt + LDS writes (swizzled) ----
#pragma unroll
        for (int i = 0; i < 8; ++i) {
            int p = i * 512 + t * 2;
            int code = p >> 5, kk = p & 31;
            unsigned pk = (unsigned)f2bf(av[i].x) | ((unsigned)f2bf(av[i].y) << 16);
            int by = kk * 2;
            int off = (by & 15) | (((by & 48)) ^ ((code & 3) << 4));
            *(unsigned*)(AsB + code * 64 + off) = pk;
        }
        {
            unsigned pk[8];
#pragma unroll
            for (int j = 0; j < 8; ++j)
                pk[j] = (unsigned)f2bf(bv[2 * j]) | ((unsigned)f2bf(bv[2 * j + 1]) << 16);
            int base = bkh * 32;
#pragma unroll
            for (int s = 0; s < 2; ++s) {
                int off = (base + s * 16) ^ ((btok & 3) << 4);
                *(uint4*)(BsB + btok * 64 + off) =
                    make_uint4(pk[s * 4], pk[s * 4 + 1], pk[s * 4 + 2], pk[s * 4 + 3]);
            }
        }
        __syncthreads();

        // ---- fragments + MFMA ----
        const int r16 = (lane >> 4) * 16;  // k-group byte offset
        short8v af[8], bfv[2];
#pragma unroll
        for (int mt = 0; mt < 8; ++mt) {
            int code = mt * 16 + (lane & 15);
            af[mt] = *(const short8v*)(AsB + code * 64 + (r16 ^ ((code & 3) << 4)));
        }
#pragma unroll
        for (int nt = 0; nt < 2; ++nt) {
            int tokl = wave * 32 + nt * 16 + (lane & 15);
            bfv[nt] = *(const short8v*)(BsB + tokl * 64 + (r16 ^ ((tokl & 3) << 4)));
        }
#pragma unroll
        for (int mt = 0; mt < 8; ++mt)
#pragma unroll
            for (int nt = 0; nt < 2; ++nt)
                acc[mt][nt] = __builtin_amdgcn_mfma_f32_16x16x32_bf16(
                    af[mt], bfv[nt], acc[mt][nt], 0, 0, 0);
    }

    // ---- epilogue: per-token top-2 over this block's 128 codes ----
    const int row4 = (lane >> 4) * 4;
#pragma unroll
    for (int nt = 0; nt < 2; ++nt) {
        u64 k1 = ~0ull, k2 = ~0ull;
#pragma unroll
        for (int mt = 0; mt < 8; ++mt) {
#pragma unroll
            for (int r = 0; r < 4; ++r) {
                int cl = mt * 16 + row4 + r;
                float d2a = cns[cl] - 2.0f * acc[mt][nt][r];
                u64 key = ((u64)packf(d2a) << 32) | (unsigned)(cblk * 128 + cl);
                if (key < k1) { k2 = k1; k1 = key; }
                else if (key < k2) { k2 = key; }
            }
        }
#pragma unroll
        for (int x = 16; x <= 32; x <<= 1) {
            u64 o1 = __shfl_xor(k1, x);
            u64 o2 = __shfl_xor(k2, x);
            u64 n1, n2;
            if (k1 < o1) { n1 = k1; n2 = (k2 < o1) ? k2 : o1; }
            else         { n1 = o1; n2 = (o2 < k1) ? o2 : k1; }
            k1 = n1; k2 = n2;
        }
        if ((lane >> 4) == 0) {
            int token = ttile * 128 + wave * 32 + nt * 16 + lane;
            top2[(size_t)token * 16 + cblk * 2]     = k1;
            top2[(size_t)token * 16 + cblk * 2 + 1] = k2;
        }
    }
}

// ---------------- kernel 2: exact fp32 refine of margin candidates ----------------
// block = 32 tokens (b,h); writes final key (idx in low 32) to keys[]
__global__ __launch_bounds__(256)
void refine_kernel(const float* __restrict__ z, const float* __restrict__ cb,
                   const float* __restrict__ cnorm, const u64* __restrict__ top2,
                   u64* __restrict__ keys) {
    __shared__ float zsm[32][261];   // pad 261: conflict-free for both phases
    __shared__ int cand[32][16];
    __shared__ int cnt[32];
    __shared__ u64 bestk[32];
    __shared__ int maxc;

    const int t = threadIdx.x;
    const int bh = blockIdx.x;
    const int b = bh >> 5, h = bh & 31;
    const int n0 = b * 1024 + h * 32;

    {   // stage z rows [32 tok][256 d]
        const int w = t & 31, dg = t >> 5;
        const float* zp = z + (size_t)b * 262144 + h * 32 + w;
#pragma unroll
        for (int i = 0; i < 32; ++i) {
            int d = dg * 32 + i;
            zsm[w][d] = zp[(size_t)d * 1024];
        }
    }
    if (t < 32) cnt[t] = 0;
    if (t == 0) maxc = 0;
    __syncthreads();

    const int tk = t >> 3, l8 = t & 7;
    {   // candidate collection: 16 keys per token, margin around approx min
        const u64* tp = top2 + ((size_t)(n0 + tk) * 16 + l8 * 2);
        u64 a = tp[0], bq = tp[1];
        u64 mn = a < bq ? a : bq;
#pragma unroll
        for (int x = 1; x < 8; x <<= 1) {
            u64 o = __shfl_xor(mn, x);
            if (o < mn) mn = o;
        }
        float thr = unpackf((unsigned)(mn >> 32)) + MARGIN;
        float da = unpackf((unsigned)(a >> 32));
        if (da <= thr) { int p = atomicAdd(&cnt[tk], 1); cand[tk][p] = (int)(a & 1023u); }
        float db = unpackf((unsigned)(bq >> 32));
        if (db <= thr) { int p = atomicAdd(&cnt[tk], 1); cand[tk][p] = (int)(bq & 1023u); }
    }
    __syncthreads();
    if (t < 32) atomicMax(&maxc, cnt[t]);
    __syncthreads();

    const int mc = maxc;
    u64 best = ~0ull;
    for (int ci = 0; ci < mc; ++ci) {
        if (ci < cnt[tk]) {
            int k = cand[tk][ci];
            const float* crow = cb + (size_t)k * 256;
            float s = 0.f;
#pragma unroll
            for (int j = 0; j < 32; ++j) {
                int d = j * 8 + l8;
                s = fmaf(zsm[tk][d], crow[d], s);
            }
#pragma unroll
            for (int x = 1; x < 8; x <<= 1) s += __shfl_xor(s, x);
            float d2 = cnorm[k] - 2.f * s;
            u64 key = ((u64)packf(d2) << 32) | (unsigned)k;
            if (key < best) best = key;
        }
    }
    if (l8 == 0) bestk[tk] = best;
    __syncthreads();
    if (t < 32) keys[n0 + t] = bestk[t];
}

// ---------------- kernel 3: gather + transpose write + idx + loss partials ----------------
__global__ __launch_bounds__(256)
void gather_kernel(const float* __restrict__ z, const float* __restrict__ cb,
                   const u64* __restrict__ keys,
                   float* __restrict__ out, float* __restrict__ partials) {
    __shared__ int sidx[32];
    __shared__ float crows[32][257];
    __shared__ float red[256];
    const int t = threadIdx.x;
    const int bh = blockIdx.x;  // 0..1023
    const int b = bh >> 5, h = bh & 31;
    const int n0 = b * 1024 + h * 32;

    if (t < 32) {
        u64 key = keys[n0 + t];
        int k = (int)(key & 0xffffffffull);
        sidx[t] = k;
        out[OUT_IDX_OFF + n0 + t] = (float)k;
    }
    __syncthreads();
    {
        const int r = t >> 3, seg = t & 7;
        const float4* src = reinterpret_cast<const float4*>(cb + (size_t)sidx[r] * D_ + seg * 32);
#pragma unroll
        for (int j = 0; j < 8; ++j) {
            float4 v = src[j];
            int d = seg * 32 + j * 4;
            crows[r][d] = v.x; crows[r][d + 1] = v.y;
            crows[r][d + 2] = v.z; crows[r][d + 3] = v.w;
        }
    }
    __syncthreads();
    const int w = t & 31, dg = t >> 5;
    const float* zrow = z + (size_t)b * (D_ * 1024) + h * 32 + w;
    float* orow = out + (size_t)b * (D_ * 1024) + h * 32 + w;
    float accl = 0.f;
#pragma unroll
    for (int i = 0; i < 32; ++i) {
        const int d = dg * 32 + i;
        const float cv = crows[w][d];
        const float zv = zrow[(size_t)d * 1024];
        orow[(size_t)d * 1024] = cv;
        const float df = cv - zv;
        accl += df * df;
    }
    red[t] = accl;
    __syncthreads();
    for (int s = 128; s > 0; s >>= 1) {
        if (t < s) red[t] += red[t + s];
        __syncthreads();
    }
    if (t == 0) partials[bh] = red[0];
}

// ---------------- kernel 4: deterministic final loss reduction ----------------
__global__ __launch_bounds__(256) void loss_kernel(const float* __restrict__ partials,
                                                   float* __restrict__ out) {
    __shared__ float red[256];
    const int t = threadIdx.x;
    float s = partials[t] + partials[t + 256] + partials[t + 512] + partials[t + 768];
    red[t] = s;
    __syncthreads();
    for (int st = 128; st > 0; st >>= 1) {
        if (t < st) red[t] += red[t + st];
        __syncthreads();
    }
    if (t == 0) out[OUT_LOSS_OFF] = red[0] * (1.25f / (float)Z_ELEMS);
}

extern "C" void kernel_launch(void* const* d_in, const int* in_sizes, int n_in,
                              void* d_out, int out_size, void* d_ws, size_t ws_size,
                              hipStream_t stream) {
    const float* z = (const float*)d_in[0];   // [32,256,32,32] f32
    const float* cb = (const float*)d_in[1];  // [1024,256] f32
    float* out = (float*)d_out;
    float* cnorm = (float*)((char*)d_ws + WS_CNORM_OFF);
    float* partials = (float*)((char*)d_ws + WS_PART_OFF);
    u64* keys = (u64*)((char*)d_ws + WS_KEYS_OFF);
    u64* top2 = (u64*)((char*)d_ws + WS_TOP2_OFF);

    cnorm_kernel<<<16, 256, 0, stream>>>(cb, cnorm);
    screen_kernel<<<2048, 256, 0, stream>>>(z, cb, cnorm, top2);
    refine_kernel<<<1024, 256, 0, stream>>>(z, cb, cnorm, top2, keys);
    gather_kernel<<<1024, 256, 0, stream>>>(z, cb, keys, out, partials);
    loss_kernel<<<1, 256, 0, stream>>>(partials, out);
}

// Round 3
// 79.173 us; speedup vs baseline: 2.9037x; 1.2220x over previous
//
#include <hip/hip_runtime.h>
#include <hip/hip_bf16.h>
#include <cstdint>

#define B_ 32
#define D_ 256
#define K_ 1024
#define N_TOK 32768
#define Z_ELEMS 8388608
#define OUT_IDX_OFF Z_ELEMS
#define OUT_LOSS_OFF (Z_ELEMS + N_TOK)

// ws layout:
//   [0,4096)             f32 cnorm[1024]
//   [4096,8192)          f32 partials[1024]
//   [8192,532480)        cb_frag bf16, fragment-order: g=((cblk*8+kc)*8+ct)*64+lane, 16B per g
//   [532480,2629632)     u32 top2[8 cblk][32768 tok][2]
#define WS_CNORM_OFF 0
#define WS_PART_OFF  4096
#define WS_CBF_OFF   8192
#define WS_TOP2_OFF  532480

#define MARGIN 1.25f

typedef __attribute__((ext_vector_type(8))) short short8v;
typedef __attribute__((ext_vector_type(4))) float f32x4;
typedef unsigned long long u64;

__device__ __forceinline__ unsigned short f2bf(float x) {
    unsigned u = __float_as_uint(x);
    return (unsigned short)((u + 0x7fffu + ((u >> 16) & 1u)) >> 16);  // RNE
}
__device__ __forceinline__ unsigned packf(float f) {
    unsigned u = __float_as_uint(f);
    return (u & 0x80000000u) ? ~u : (u | 0x80000000u);  // order-preserving bits
}
__device__ __forceinline__ float unpackf(unsigned p) {
    unsigned u = (p & 0x80000000u) ? (p & 0x7fffffffu) : ~p;
    return __uint_as_float(u);
}

// ---------------- kernel 0: cnorm (fp32) + cb -> bf16 fragment order ----------------
__global__ __launch_bounds__(256)
void prep_kernel(const float* __restrict__ cb, float* __restrict__ cnorm,
                 unsigned char* __restrict__ cbf) {
    const int t = threadIdx.x;
    const int blk = blockIdx.x;  // 16 blocks
    {   // cnorm: 64 codes per block, 4 threads each
        int k = blk * 64 + (t >> 2);
        int part = t & 3;
        const float4* row = reinterpret_cast<const float4*>(cb + k * D_);
        float s = 0.f;
#pragma unroll
        for (int j = 0; j < 16; ++j) {
            float4 v = row[part * 16 + j];
            s += v.x * v.x + v.y * v.y + v.z * v.z + v.w * v.w;
        }
        s += __shfl_xor(s, 1);
        s += __shfl_xor(s, 2);
        if (part == 0) cnorm[k] = s;
    }
    // fragment reorder: unit g -> (cblk,kc,ct,lane); 8 units per thread
#pragma unroll
    for (int w = 0; w < 8; ++w) {
        int g = blk * 2048 + w * 256 + t;
        int lane = g & 63, ct = (g >> 6) & 7, kc = (g >> 9) & 7, cblk = g >> 12;
        int code = cblk * 128 + ct * 16 + (lane & 15);
        int d0 = kc * 32 + (lane >> 4) * 8;
        const float* src = cb + code * 256 + d0;
        float4 a = *reinterpret_cast<const float4*>(src);
        float4 b2 = *reinterpret_cast<const float4*>(src + 4);
        uint4 pk;
        pk.x = (unsigned)f2bf(a.x) | ((unsigned)f2bf(a.y) << 16);
        pk.y = (unsigned)f2bf(a.z) | ((unsigned)f2bf(a.w) << 16);
        pk.z = (unsigned)f2bf(b2.x) | ((unsigned)f2bf(b2.y) << 16);
        pk.w = (unsigned)f2bf(b2.z) | ((unsigned)f2bf(b2.w) << 16);
        *reinterpret_cast<uint4*>(cbf + (size_t)g * 16) = pk;
    }
}

// ---------------- kernel 1: bf16 MFMA screen, 64 tokens x 1024 codes ----------------
// 512 blocks x 256 thr (4 waves); wave = 16 tokens x 1024 codes; z staged once
__global__ __launch_bounds__(256, 2)
void screen_kernel(const float* __restrict__ z, const unsigned char* __restrict__ cbf,
                   const float* __restrict__ cnorm, unsigned* __restrict__ top2) {
    __shared__ __align__(16) unsigned char zfB[32768];  // [tt 4][kc 8][lane 64][8] bf16
    __shared__ float cns[1024];

    const int t = threadIdx.x;
    const int lane = t & 63;
    const int wv = t >> 6;
    const int blk = blockIdx.x;
    const int b = blk >> 4;
    const int hw0 = (blk & 15) << 6;
    const float* zb = z + ((size_t)b << 18) + hw0;

    for (int i = t; i < 1024; i += 256) cns[i] = cnorm[i];

    {   // stage 64 tok x 256 d -> bf16 fragments (once)
        const int stok = t & 63;
        const int sh = t >> 6;
        const int tt = stok >> 4;
#pragma unroll
        for (int uu = 0; uu < 8; ++uu) {
            int u = uu * 4 + sh;       // 8-d chunk 0..31
            int d0 = u * 8;
            float v[8];
#pragma unroll
            for (int j = 0; j < 8; ++j) v[j] = zb[(size_t)(d0 + j) * 1024 + stok];
            uint4 pk;
            pk.x = (unsigned)f2bf(v[0]) | ((unsigned)f2bf(v[1]) << 16);
            pk.y = (unsigned)f2bf(v[2]) | ((unsigned)f2bf(v[3]) << 16);
            pk.z = (unsigned)f2bf(v[4]) | ((unsigned)f2bf(v[5]) << 16);
            pk.w = (unsigned)f2bf(v[6]) | ((unsigned)f2bf(v[7]) << 16);
            int slot = ((u & 3) << 4) | (stok & 15);
            *reinterpret_cast<uint4*>(zfB + tt * 8192 + (u >> 2) * 1024 + slot * 16) = pk;
        }
    }
    __syncthreads();

    const unsigned char* zrd = zfB + wv * 8192 + lane * 16;
    const int rbase = (lane >> 4) << 2;

    for (int cblk = 0; cblk < 8; ++cblk) {
        f32x4 acc[8];
#pragma unroll
        for (int mt = 0; mt < 8; ++mt) acc[mt] = (f32x4){0.f, 0.f, 0.f, 0.f};
        const unsigned char* abase = cbf + (size_t)cblk * 65536 + lane * 16;
#pragma unroll
        for (int kc = 0; kc < 8; ++kc) {
            short8v bfv = *reinterpret_cast<const short8v*>(zrd + kc * 1024);
#pragma unroll
            for (int mt = 0; mt < 8; ++mt) {
                short8v af = *reinterpret_cast<const short8v*>(abase + (kc * 8 + mt) * 1024);
                acc[mt] = __builtin_amdgcn_mfma_f32_16x16x32_bf16(af, bfv, acc[mt], 0, 0, 0);
            }
        }
        // top-2 over this cblk's 128 codes
        unsigned k1 = 0xFFFFFFFFu, k2 = 0xFFFFFFFFu;
#pragma unroll
        for (int mt = 0; mt < 8; ++mt) {
#pragma unroll
            for (int r = 0; r < 4; ++r) {
                int code = cblk * 128 + mt * 16 + rbase + r;
                float d2a = fmaf(-2.0f, acc[mt][r], cns[code]);
                unsigned key = (packf(d2a) & 0xFFFFFC00u) | (unsigned)code;
                if (key < k1) { k2 = k1; k1 = key; }
                else if (key < k2) { k2 = key; }
            }
        }
#pragma unroll
        for (int x = 16; x <= 32; x <<= 1) {
            unsigned o1 = __shfl_xor(k1, x);
            unsigned o2 = __shfl_xor(k2, x);
            unsigned n1, n2;
            if (k1 < o1) { n1 = k1; n2 = (k2 < o1) ? k2 : o1; }
            else         { n1 = o1; n2 = (o2 < k1) ? o2 : k1; }
            k1 = n1; k2 = n2;
        }
        if (lane < 16) {
            int token = blk * 64 + wv * 16 + lane;
            *reinterpret_cast<uint2*>(top2 + ((size_t)cblk * N_TOK + token) * 2) =
                make_uint2(k1, k2);
        }
    }
}

// ---------------- kernel 2: fused exact refine + gather + loss partials ----------------
__global__ __launch_bounds__(256)
void refgather_kernel(const float* __restrict__ z, const float* __restrict__ cb,
                      const float* __restrict__ cnorm, const unsigned* __restrict__ top2,
                      float* __restrict__ out, float* __restrict__ partials) {
    __shared__ float zsm[32][261];
    __shared__ float crows[32][257];
    __shared__ int cand[32][16];
    __shared__ int cnt[32];
    __shared__ u64 bestk[32];
    __shared__ int sidx[32];
    __shared__ float red[256];
    __shared__ int maxc;

    const int t = threadIdx.x;
    const int bh = blockIdx.x;  // 0..1023
    const int b = bh >> 5, h = bh & 31;
    const int n0 = b * 1024 + h * 32;
    const int w = t & 31, dg = t >> 5;

    {   // stage z rows (coalesced 128B segments)
        const float* zp = z + ((size_t)b << 18) + h * 32 + w;
#pragma unroll
        for (int i = 0; i < 32; ++i) {
            int d = dg * 32 + i;
            zsm[w][d] = zp[(size_t)d * 1024];
        }
    }
    if (t < 32) cnt[t] = 0;
    if (t == 0) maxc = 0;
    __syncthreads();

    const int tk = t >> 3, l8 = t & 7;
    {   // candidate collection from per-cblk top-2
        uint2 kk = *reinterpret_cast<const uint2*>(
            top2 + ((size_t)l8 * N_TOK + (n0 + tk)) * 2);
        unsigned mn = kk.x;  // k1 <= k2
#pragma unroll
        for (int x = 1; x < 8; x <<= 1) {
            unsigned o = __shfl_xor(mn, x);
            if (o < mn) mn = o;
        }
        float thr = unpackf(mn & 0xFFFFFC00u) + MARGIN;
        float da = unpackf(kk.x & 0xFFFFFC00u);
        if (da <= thr) { int p = atomicAdd(&cnt[tk], 1); cand[tk][p] = (int)(kk.x & 1023u); }
        float db = unpackf(kk.y & 0xFFFFFC00u);
        if (db <= thr) { int p = atomicAdd(&cnt[tk], 1); cand[tk][p] = (int)(kk.y & 1023u); }
    }
    __syncthreads();
    if (t < 32) atomicMax(&maxc, cnt[t]);
    __syncthreads();

    const int mc = maxc;
    u64 best = ~0ull;
    for (int ci = 0; ci < mc; ++ci) {
        if (ci < cnt[tk]) {
            int k = cand[tk][ci];
            const float* crow = cb + (size_t)k * 256;
            float s = 0.f;
#pragma unroll
            for (int j = 0; j < 32; ++j) {
                int d = j * 8 + l8;
                s = fmaf(zsm[tk][d], crow[d], s);
            }
#pragma unroll
            for (int x = 1; x < 8; x <<= 1) s += __shfl_xor(s, x);
            float d2 = cnorm[k] - 2.f * s;
            u64 key = ((u64)packf(d2) << 32) | (unsigned)k;
            if (key < best) best = key;
        }
    }
    if (l8 == 0) bestk[tk] = best;
    __syncthreads();
    if (t < 32) {
        int k = (int)(bestk[t] & 1023ull);
        sidx[t] = k;
        out[OUT_IDX_OFF + n0 + t] = (float)k;
    }
    __syncthreads();
    {   // stage chosen codebook rows (fp32)
        const int r = t & 31, q = t >> 5;
        const float4* src = reinterpret_cast<const float4*>(cb + (size_t)sidx[r] * 256 + q * 32);
#pragma unroll
        for (int j = 0; j < 8; ++j) {
            float4 v = src[j];
            int d = q * 32 + j * 4;
            crows[r][d] = v.x; crows[r][d + 1] = v.y;
            crows[r][d + 2] = v.z; crows[r][d + 3] = v.w;
        }
    }
    __syncthreads();
    float accl = 0.f;
    float* orow = out + ((size_t)b << 18) + h * 32 + w;
#pragma unroll
    for (int i = 0; i < 32; ++i) {
        const int d = dg * 32 + i;
        const float cv = crows[w][d];
        const float zv = zsm[w][d];
        orow[(size_t)d * 1024] = cv;
        const float df = cv - zv;
        accl += df * df;
    }
    red[t] = accl;
    __syncthreads();
    for (int s = 128; s > 0; s >>= 1) {
        if (t < s) red[t] += red[t + s];
        __syncthreads();
    }
    if (t == 0) partials[bh] = red[0];
}

// ---------------- kernel 3: deterministic final loss reduction ----------------
__global__ __launch_bounds__(256) void loss_kernel(const float* __restrict__ partials,
                                                   float* __restrict__ out) {
    __shared__ float red[256];
    const int t = threadIdx.x;
    float s = partials[t] + partials[t + 256] + partials[t + 512] + partials[t + 768];
    red[t] = s;
    __syncthreads();
    for (int st = 128; st > 0; st >>= 1) {
        if (t < st) red[t] += red[t + st];
        __syncthreads();
    }
    if (t == 0) out[OUT_LOSS_OFF] = red[0] * (1.25f / (float)Z_ELEMS);
}

extern "C" void kernel_launch(void* const* d_in, const int* in_sizes, int n_in,
                              void* d_out, int out_size, void* d_ws, size_t ws_size,
                              hipStream_t stream) {
    const float* z = (const float*)d_in[0];   // [32,256,32,32] f32
    const float* cb = (const float*)d_in[1];  // [1024,256] f32
    float* out = (float*)d_out;
    float* cnorm = (float*)((char*)d_ws + WS_CNORM_OFF);
    float* partials = (float*)((char*)d_ws + WS_PART_OFF);
    unsigned char* cbf = (unsigned char*)d_ws + WS_CBF_OFF;
    unsigned* top2 = (unsigned*)((char*)d_ws + WS_TOP2_OFF);

    prep_kernel<<<16, 256, 0, stream>>>(cb, cnorm, cbf);
    screen_kernel<<<512, 256, 0, stream>>>(z, cbf, cnorm, top2);
    refgather_kernel<<<1024, 256, 0, stream>>>(z, cb, cnorm, top2, out, partials);
    loss_kernel<<<1, 256, 0, stream>>>(partials, out);
}

// Round 4
// 70.778 us; speedup vs baseline: 3.2481x; 1.1186x over previous
//
#include <hip/hip_runtime.h>
#include <hip/hip_bf16.h>
#include <cstdint>

#define B_ 32
#define D_ 256
#define K_ 1024
#define N_TOK 32768
#define Z_ELEMS 8388608
#define OUT_IDX_OFF Z_ELEMS
#define OUT_LOSS_OFF (Z_ELEMS + N_TOK)

// ws layout:
//   [0,4096)             f32 cnorm[1024]
//   [4096,8192)          f32 partials[1024]
//   [8192,532480)        cb_frag bf16, fragment-order: g=((cblk*8+kc)*8+ct)*64+lane, 16B per g
//   [532480,2629632)     u32 top2[8 cblk][32768 tok][2]
#define WS_CNORM_OFF 0
#define WS_PART_OFF  4096
#define WS_CBF_OFF   8192
#define WS_TOP2_OFF  532480

#define MARGIN 1.25f

typedef __attribute__((ext_vector_type(8))) short short8v;
typedef __attribute__((ext_vector_type(4))) float f32x4;
typedef unsigned long long u64;

__device__ __forceinline__ unsigned short f2bf(float x) {
    unsigned u = __float_as_uint(x);
    return (unsigned short)((u + 0x7fffu + ((u >> 16) & 1u)) >> 16);  // RNE
}
__device__ __forceinline__ unsigned packf(float f) {
    unsigned u = __float_as_uint(f);
    return (u & 0x80000000u) ? ~u : (u | 0x80000000u);  // order-preserving bits
}
__device__ __forceinline__ float unpackf(unsigned p) {
    unsigned u = (p & 0x80000000u) ? (p & 0x7fffffffu) : ~p;
    return __uint_as_float(u);
}

// ---------------- kernel 0: cnorm (fp32) + cb -> bf16 fragment order ----------------
__global__ __launch_bounds__(256)
void prep_kernel(const float* __restrict__ cb, float* __restrict__ cnorm,
                 unsigned char* __restrict__ cbf) {
    const int t = threadIdx.x;
    const int blk = blockIdx.x;  // 16 blocks
    {   // cnorm: 64 codes per block, 4 threads each
        int k = blk * 64 + (t >> 2);
        int part = t & 3;
        const float4* row = reinterpret_cast<const float4*>(cb + k * D_);
        float s = 0.f;
#pragma unroll
        for (int j = 0; j < 16; ++j) {
            float4 v = row[part * 16 + j];
            s += v.x * v.x + v.y * v.y + v.z * v.z + v.w * v.w;
        }
        s += __shfl_xor(s, 1);
        s += __shfl_xor(s, 2);
        if (part == 0) cnorm[k] = s;
    }
    // fragment reorder: unit g -> (cblk,kc,ct,lane); 8 units per thread
#pragma unroll
    for (int w = 0; w < 8; ++w) {
        int g = blk * 2048 + w * 256 + t;
        int lane = g & 63, ct = (g >> 6) & 7, kc = (g >> 9) & 7, cblk = g >> 12;
        int code = cblk * 128 + ct * 16 + (lane & 15);
        int d0 = kc * 32 + (lane >> 4) * 8;
        const float* src = cb + code * 256 + d0;
        float4 a = *reinterpret_cast<const float4*>(src);
        float4 b2 = *reinterpret_cast<const float4*>(src + 4);
        uint4 pk;
        pk.x = (unsigned)f2bf(a.x) | ((unsigned)f2bf(a.y) << 16);
        pk.y = (unsigned)f2bf(a.z) | ((unsigned)f2bf(a.w) << 16);
        pk.z = (unsigned)f2bf(b2.x) | ((unsigned)f2bf(b2.y) << 16);
        pk.w = (unsigned)f2bf(b2.z) | ((unsigned)f2bf(b2.w) << 16);
        *reinterpret_cast<uint4*>(cbf + (size_t)g * 16) = pk;
    }
}

// ---------------- kernel 1: bf16 MFMA screen ----------------
// 512 blocks x 256 thr (4 waves). Block = 64 tokens x 1024 codes.
// Wave wv covers code-quarter wv (2 cblks of 128). 64 tok x 256 codes per wave:
// A-traffic per wave = 128 KB (4x reuse vs round-3), total 256 MB from L2.
__global__ __launch_bounds__(256, 2)
void screen_kernel(const float* __restrict__ z, const unsigned char* __restrict__ cbf,
                   const float* __restrict__ cnorm, unsigned* __restrict__ top2) {
    __shared__ __align__(16) unsigned char zfB[32768];  // [kc 8][ntg 4][lane 64][16B]
    __shared__ float cns[1024];

    const int t = threadIdx.x;
    const int lane = t & 63;
    const int wv = t >> 6;
    const int blk = blockIdx.x;
    const int b = blk >> 4;
    const int hw0 = (blk & 15) << 6;
    const float* zb = z + ((size_t)b << 18) + hw0;

    for (int i = t; i < 1024; i += 256) cns[i] = cnorm[i];

    {   // stage 64 tok x 256 d -> bf16 B-fragments (once per block)
        const int tok = t & 63;
        const int dseg = t >> 6;   // 64-d segment
#pragma unroll
        for (int u = 0; u < 8; ++u) {
            int d0 = dseg * 64 + u * 8;
            float v[8];
#pragma unroll
            for (int j = 0; j < 8; ++j) v[j] = zb[(size_t)(d0 + j) * 1024 + tok];
            uint4 pk;
            pk.x = (unsigned)f2bf(v[0]) | ((unsigned)f2bf(v[1]) << 16);
            pk.y = (unsigned)f2bf(v[2]) | ((unsigned)f2bf(v[3]) << 16);
            pk.z = (unsigned)f2bf(v[4]) | ((unsigned)f2bf(v[5]) << 16);
            pk.w = (unsigned)f2bf(v[6]) | ((unsigned)f2bf(v[7]) << 16);
            int kc = d0 >> 5;                 // dseg*2 + (u>>2)
            int slot = (kc * 4 + (tok >> 4)) * 64 + (u & 3) * 16 + (tok & 15);
            *reinterpret_cast<uint4*>(zfB + slot * 16) = pk;
        }
    }
    __syncthreads();

    const int rbase = (lane >> 4) << 2;

#pragma unroll
    for (int cb2 = 0; cb2 < 2; ++cb2) {
        const int cblk = wv * 2 + cb2;
        const unsigned char* abase = cbf + (size_t)cblk * 65536 + lane * 16;

        f32x4 acc[8][4];
#pragma unroll
        for (int mt = 0; mt < 8; ++mt)
#pragma unroll
            for (int nt = 0; nt < 4; ++nt) acc[mt][nt] = (f32x4){0.f, 0.f, 0.f, 0.f};

#pragma unroll
        for (int kc = 0; kc < 8; ++kc) {
            short8v bfv[4];
#pragma unroll
            for (int nt = 0; nt < 4; ++nt)
                bfv[nt] = *reinterpret_cast<const short8v*>(zfB + (kc * 4 + nt) * 1024 + lane * 16);
            short8v af[8];
#pragma unroll
            for (int mt = 0; mt < 8; ++mt)
                af[mt] = *reinterpret_cast<const short8v*>(abase + (kc * 8 + mt) * 1024);
#pragma unroll
            for (int mt = 0; mt < 8; ++mt)
#pragma unroll
                for (int nt = 0; nt < 4; ++nt)
                    acc[mt][nt] = __builtin_amdgcn_mfma_f32_16x16x32_bf16(
                        af[mt], bfv[nt], acc[mt][nt], 0, 0, 0);
        }

        // epilogue: per-token top-2 over this cblk's 128 codes
#pragma unroll
        for (int nt = 0; nt < 4; ++nt) {
            unsigned k1 = 0xFFFFFFFFu, k2 = 0xFFFFFFFFu;
#pragma unroll
            for (int mt = 0; mt < 8; ++mt) {
#pragma unroll
                for (int r = 0; r < 4; ++r) {
                    int code = cblk * 128 + mt * 16 + rbase + r;
                    float d2a = fmaf(-2.0f, acc[mt][nt][r], cns[code]);
                    unsigned key = (packf(d2a) & 0xFFFFFC00u) | (unsigned)code;
                    if (key < k1) { k2 = k1; k1 = key; }
                    else if (key < k2) { k2 = key; }
                }
            }
#pragma unroll
            for (int x = 16; x <= 32; x <<= 1) {
                unsigned o1 = __shfl_xor(k1, x);
                unsigned o2 = __shfl_xor(k2, x);
                unsigned n1, n2;
                if (k1 < o1) { n1 = k1; n2 = (k2 < o1) ? k2 : o1; }
                else         { n1 = o1; n2 = (o2 < k1) ? o2 : k1; }
                k1 = n1; k2 = n2;
            }
            if (lane < 16) {
                int token = blk * 64 + nt * 16 + lane;
                *reinterpret_cast<uint2*>(top2 + ((size_t)cblk * N_TOK + token) * 2) =
                    make_uint2(k1, k2);
            }
        }
    }
}

// ---------------- kernel 2: fused exact refine + gather + loss partials ----------------
__global__ __launch_bounds__(256)
void refgather_kernel(const float* __restrict__ z, const float* __restrict__ cb,
                      const float* __restrict__ cnorm, const unsigned* __restrict__ top2,
                      float* __restrict__ out, float* __restrict__ partials) {
    __shared__ float zsm[32][261];
    __shared__ float crows[32][257];
    __shared__ int cand[32][16];
    __shared__ int cnt[32];
    __shared__ u64 bestk[32];
    __shared__ int sidx[32];
    __shared__ float red[256];
    __shared__ int maxc;

    const int t = threadIdx.x;
    const int bh = blockIdx.x;  // 0..1023
    const int b = bh >> 5, h = bh & 31;
    const int n0 = b * 1024 + h * 32;
    const int w = t & 31, dg = t >> 5;

    {   // stage z rows (coalesced 128B segments)
        const float* zp = z + ((size_t)b << 18) + h * 32 + w;
#pragma unroll
        for (int i = 0; i < 32; ++i) {
            int d = dg * 32 + i;
            zsm[w][d] = zp[(size_t)d * 1024];
        }
    }
    if (t < 32) cnt[t] = 0;
    if (t == 0) maxc = 0;
    __syncthreads();

    const int tk = t >> 3, l8 = t & 7;
    {   // candidate collection from per-cblk top-2
        uint2 kk = *reinterpret_cast<const uint2*>(
            top2 + ((size_t)l8 * N_TOK + (n0 + tk)) * 2);
        unsigned mn = kk.x;  // k1 <= k2
#pragma unroll
        for (int x = 1; x < 8; x <<= 1) {
            unsigned o = __shfl_xor(mn, x);
            if (o < mn) mn = o;
        }
        float thr = unpackf(mn & 0xFFFFFC00u) + MARGIN;
        float da = unpackf(kk.x & 0xFFFFFC00u);
        if (da <= thr) { int p = atomicAdd(&cnt[tk], 1); cand[tk][p] = (int)(kk.x & 1023u); }
        float db = unpackf(kk.y & 0xFFFFFC00u);
        if (db <= thr) { int p = atomicAdd(&cnt[tk], 1); cand[tk][p] = (int)(kk.y & 1023u); }
    }
    __syncthreads();
    if (t < 32) atomicMax(&maxc, cnt[t]);
    __syncthreads();

    const int mc = maxc;
    u64 best = ~0ull;
    for (int ci = 0; ci < mc; ++ci) {
        if (ci < cnt[tk]) {
            int k = cand[tk][ci];
            const float* crow = cb + (size_t)k * 256;
            float s = 0.f;
#pragma unroll
            for (int j = 0; j < 32; ++j) {
                int d = j * 8 + l8;
                s = fmaf(zsm[tk][d], crow[d], s);
            }
#pragma unroll
            for (int x = 1; x < 8; x <<= 1) s += __shfl_xor(s, x);
            float d2 = cnorm[k] - 2.f * s;
            u64 key = ((u64)packf(d2) << 32) | (unsigned)k;
            if (key < best) best = key;
        }
    }
    if (l8 == 0) bestk[tk] = best;
    __syncthreads();
    if (t < 32) {
        int k = (int)(bestk[t] & 1023ull);
        sidx[t] = k;
        out[OUT_IDX_OFF + n0 + t] = (float)k;
    }
    __syncthreads();
    {   // stage chosen codebook rows (fp32)
        const int r = t & 31, q = t >> 5;
        const float4* src = reinterpret_cast<const float4*>(cb + (size_t)sidx[r] * 256 + q * 32);
#pragma unroll
        for (int j = 0; j < 8; ++j) {
            float4 v = src[j];
            int d = q * 32 + j * 4;
            crows[r][d] = v.x; crows[r][d + 1] = v.y;
            crows[r][d + 2] = v.z; crows[r][d + 3] = v.w;
        }
    }
    __syncthreads();
    float accl = 0.f;
    float* orow = out + ((size_t)b << 18) + h * 32 + w;
#pragma unroll
    for (int i = 0; i < 32; ++i) {
        const int d = dg * 32 + i;
        const float cv = crows[w][d];
        const float zv = zsm[w][d];
        orow[(size_t)d * 1024] = cv;
        const float df = cv - zv;
        accl += df * df;
    }
    red[t] = accl;
    __syncthreads();
    for (int s = 128; s > 0; s >>= 1) {
        if (t < s) red[t] += red[t + s];
        __syncthreads();
    }
    if (t == 0) partials[bh] = red[0];
}

// ---------------- kernel 3: deterministic final loss reduction ----------------
__global__ __launch_bounds__(256) void loss_kernel(const float* __restrict__ partials,
                                                   float* __restrict__ out) {
    __shared__ float red[256];
    const int t = threadIdx.x;
    float s = partials[t] + partials[t + 256] + partials[t + 512] + partials[t + 768];
    red[t] = s;
    __syncthreads();
    for (int st = 128; st > 0; st >>= 1) {
        if (t < st) red[t] += red[t + st];
        __syncthreads();
    }
    if (t == 0) out[OUT_LOSS_OFF] = red[0] * (1.25f / (float)Z_ELEMS);
}

extern "C" void kernel_launch(void* const* d_in, const int* in_sizes, int n_in,
                              void* d_out, int out_size, void* d_ws, size_t ws_size,
                              hipStream_t stream) {
    const float* z = (const float*)d_in[0];   // [32,256,32,32] f32
    const float* cb = (const float*)d_in[1];  // [1024,256] f32
    float* out = (float*)d_out;
    float* cnorm = (float*)((char*)d_ws + WS_CNORM_OFF);
    float* partials = (float*)((char*)d_ws + WS_PART_OFF);
    unsigned char* cbf = (unsigned char*)d_ws + WS_CBF_OFF;
    unsigned* top2 = (unsigned*)((char*)d_ws + WS_TOP2_OFF);

    prep_kernel<<<16, 256, 0, stream>>>(cb, cnorm, cbf);
    screen_kernel<<<512, 256, 0, stream>>>(z, cbf, cnorm, top2);
    refgather_kernel<<<1024, 256, 0, stream>>>(z, cb, cnorm, top2, out, partials);
    loss_kernel<<<1, 256, 0, stream>>>(partials, out);
}

// Round 5
// 70.325 us; speedup vs baseline: 3.2690x; 1.0064x over previous
//
#include <hip/hip_runtime.h>
#include <hip/hip_bf16.h>
#include <cstdint>

#define B_ 32
#define D_ 256
#define K_ 1024
#define N_TOK 32768
#define Z_ELEMS 8388608
#define OUT_IDX_OFF Z_ELEMS
#define OUT_LOSS_OFF (Z_ELEMS + N_TOK)

// ws layout:
//   [0,4096)             f32 cnorm[1024]
//   [4096,8192)          f32 partials[1024]
//   [8192,532480)        cb_frag bf16, fragment-order: g=((cblk*8+kc)*8+ct)*64+lane, 16B per g
//   [532480,2629632)     u32 top2[8 cblk][32768 tok][2]
#define WS_CNORM_OFF 0
#define WS_PART_OFF  4096
#define WS_CBF_OFF   8192
#define WS_TOP2_OFF  532480

#define MARGIN 1.25f

typedef __attribute__((ext_vector_type(8))) short short8v;
typedef __attribute__((ext_vector_type(4))) float f32x4;
typedef unsigned long long u64;

__device__ __forceinline__ unsigned short f2bf(float x) {
    unsigned u = __float_as_uint(x);
    return (unsigned short)((u + 0x7fffu + ((u >> 16) & 1u)) >> 16);  // RNE
}
__device__ __forceinline__ unsigned packf(float f) {
    unsigned u = __float_as_uint(f);
    return (u & 0x80000000u) ? ~u : (u | 0x80000000u);  // order-preserving bits
}
__device__ __forceinline__ float unpackf(unsigned p) {
    unsigned u = (p & 0x80000000u) ? (p & 0x7fffffffu) : ~p;
    return __uint_as_float(u);
}

// ---------------- kernel 0: cnorm (fp32) + cb -> bf16 fragment order ----------------
__global__ __launch_bounds__(256)
void prep_kernel(const float* __restrict__ cb, float* __restrict__ cnorm,
                 unsigned char* __restrict__ cbf) {
    const int t = threadIdx.x;
    const int blk = blockIdx.x;  // 16 blocks
    {   // cnorm: 64 codes per block, 4 threads each
        int k = blk * 64 + (t >> 2);
        int part = t & 3;
        const float4* row = reinterpret_cast<const float4*>(cb + k * D_);
        float s = 0.f;
#pragma unroll
        for (int j = 0; j < 16; ++j) {
            float4 v = row[part * 16 + j];
            s += v.x * v.x + v.y * v.y + v.z * v.z + v.w * v.w;
        }
        s += __shfl_xor(s, 1);
        s += __shfl_xor(s, 2);
        if (part == 0) cnorm[k] = s;
    }
    // fragment reorder: unit g -> (cblk,kc,ct,lane); 8 units per thread
#pragma unroll
    for (int w = 0; w < 8; ++w) {
        int g = blk * 2048 + w * 256 + t;
        int lane = g & 63, ct = (g >> 6) & 7, kc = (g >> 9) & 7, cblk = g >> 12;
        int code = cblk * 128 + ct * 16 + (lane & 15);
        int d0 = kc * 32 + (lane >> 4) * 8;
        const float* src = cb + code * 256 + d0;
        float4 a = *reinterpret_cast<const float4*>(src);
        float4 b2 = *reinterpret_cast<const float4*>(src + 4);
        uint4 pk;
        pk.x = (unsigned)f2bf(a.x) | ((unsigned)f2bf(a.y) << 16);
        pk.y = (unsigned)f2bf(a.z) | ((unsigned)f2bf(a.w) << 16);
        pk.z = (unsigned)f2bf(b2.x) | ((unsigned)f2bf(b2.y) << 16);
        pk.w = (unsigned)f2bf(b2.z) | ((unsigned)f2bf(b2.w) << 16);
        *reinterpret_cast<uint4*>(cbf + (size_t)g * 16) = pk;
    }
}

// ---------------- kernel 1: bf16 MFMA screen, reg-double-buffered A prefetch ----------------
// 512 blocks x 256 thr (4 waves). Block = 64 tokens x 1024 codes.
// Wave wv covers cblks {2wv, 2wv+1}: 64 tok x 256 codes. 16 pipelined (cblk,kc) steps.
__global__ __launch_bounds__(256, 2)
void screen_kernel(const float* __restrict__ z, const unsigned char* __restrict__ cbf,
                   const float* __restrict__ cnorm, unsigned* __restrict__ top2) {
    __shared__ __align__(16) unsigned char zfB[32768];  // [kc 8][ntg 4][lane 64][16B]
    __shared__ float cns[1024];

    const int t = threadIdx.x;
    const int lane = t & 63;
    const int wv = t >> 6;
    const int blk = blockIdx.x;
    const int b = blk >> 4;
    const int hw0 = (blk & 15) << 6;
    const float* zb = z + ((size_t)b << 18) + hw0;

    const unsigned char* abase0 = cbf + (size_t)(wv * 2) * 65536 + lane * 16;

    // prologue A prefetch (step 0: cblk=2wv, kc=0) — overlaps the staging phase
    short8v afA[8], afB[8];
#pragma unroll
    for (int mt = 0; mt < 8; ++mt)
        afA[mt] = *reinterpret_cast<const short8v*>(abase0 + mt * 1024);

    for (int i = t; i < 1024; i += 256) cns[i] = cnorm[i];

    {   // stage 64 tok x 256 d -> bf16 B-fragments (once per block)
        const int tok = t & 63;
        const int dseg = t >> 6;   // 64-d segment
#pragma unroll
        for (int u = 0; u < 8; ++u) {
            int d0 = dseg * 64 + u * 8;
            float v[8];
#pragma unroll
            for (int j = 0; j < 8; ++j) v[j] = zb[(size_t)(d0 + j) * 1024 + tok];
            uint4 pk;
            pk.x = (unsigned)f2bf(v[0]) | ((unsigned)f2bf(v[1]) << 16);
            pk.y = (unsigned)f2bf(v[2]) | ((unsigned)f2bf(v[3]) << 16);
            pk.z = (unsigned)f2bf(v[4]) | ((unsigned)f2bf(v[5]) << 16);
            pk.w = (unsigned)f2bf(v[6]) | ((unsigned)f2bf(v[7]) << 16);
            int kc = d0 >> 5;                 // dseg*2 + (u>>2)
            int slot = (kc * 4 + (tok >> 4)) * 64 + (u & 3) * 16 + (tok & 15);
            *reinterpret_cast<uint4*>(zfB + slot * 16) = pk;
        }
    }
    __syncthreads();

    const int rbase = (lane >> 4) << 2;

#pragma unroll
    for (int cb2 = 0; cb2 < 2; ++cb2) {
        const int cblk = wv * 2 + cb2;
        const unsigned char* abase = cbf + (size_t)cblk * 65536 + lane * 16;

        f32x4 acc[8][4];
#pragma unroll
        for (int mt = 0; mt < 8; ++mt)
#pragma unroll
            for (int nt = 0; nt < 4; ++nt) acc[mt][nt] = (f32x4){0.f, 0.f, 0.f, 0.f};

#pragma unroll
        for (int kc = 0; kc < 8; ++kc) {
            // prefetch step+1 into the inactive buffer (static buffer choice: kc parity)
            if (!(cb2 == 1 && kc == 7)) {
                const unsigned char* pb =
                    (kc < 7) ? (abase + (kc + 1) * 8192)
                             : (cbf + (size_t)(cblk + 1) * 65536 + lane * 16);
                if ((kc & 1) == 0) {
#pragma unroll
                    for (int mt = 0; mt < 8; ++mt)
                        afB[mt] = *reinterpret_cast<const short8v*>(pb + mt * 1024);
                } else {
#pragma unroll
                    for (int mt = 0; mt < 8; ++mt)
                        afA[mt] = *reinterpret_cast<const short8v*>(pb + mt * 1024);
                }
            }
            short8v bfv[4];
#pragma unroll
            for (int nt = 0; nt < 4; ++nt)
                bfv[nt] = *reinterpret_cast<const short8v*>(zfB + (kc * 4 + nt) * 1024 + lane * 16);
            if ((kc & 1) == 0) {
#pragma unroll
                for (int mt = 0; mt < 8; ++mt)
#pragma unroll
                    for (int nt = 0; nt < 4; ++nt)
                        acc[mt][nt] = __builtin_amdgcn_mfma_f32_16x16x32_bf16(
                            afA[mt], bfv[nt], acc[mt][nt], 0, 0, 0);
            } else {
#pragma unroll
                for (int mt = 0; mt < 8; ++mt)
#pragma unroll
                    for (int nt = 0; nt < 4; ++nt)
                        acc[mt][nt] = __builtin_amdgcn_mfma_f32_16x16x32_bf16(
                            afB[mt], bfv[nt], acc[mt][nt], 0, 0, 0);
            }
        }

        // epilogue: per-token top-2 over this cblk's 128 codes
        // (also hides the already-issued next-cblk A prefetch)
#pragma unroll
        for (int nt = 0; nt < 4; ++nt) {
            unsigned k1 = 0xFFFFFFFFu, k2 = 0xFFFFFFFFu;
#pragma unroll
            for (int mt = 0; mt < 8; ++mt) {
#pragma unroll
                for (int r = 0; r < 4; ++r) {
                    int code = cblk * 128 + mt * 16 + rbase + r;
                    float d2a = fmaf(-2.0f, acc[mt][nt][r], cns[code]);
                    unsigned key = (packf(d2a) & 0xFFFFFC00u) | (unsigned)code;
                    if (key < k1) { k2 = k1; k1 = key; }
                    else if (key < k2) { k2 = key; }
                }
            }
#pragma unroll
            for (int x = 16; x <= 32; x <<= 1) {
                unsigned o1 = __shfl_xor(k1, x);
                unsigned o2 = __shfl_xor(k2, x);
                unsigned n1, n2;
                if (k1 < o1) { n1 = k1; n2 = (k2 < o1) ? k2 : o1; }
                else         { n1 = o1; n2 = (o2 < k1) ? o2 : k1; }
                k1 = n1; k2 = n2;
            }
            if (lane < 16) {
                int token = blk * 64 + nt * 16 + lane;
                *reinterpret_cast<uint2*>(top2 + ((size_t)cblk * N_TOK + token) * 2) =
                    make_uint2(k1, k2);
            }
        }
    }
}

// ---------------- kernel 2: fused exact refine + gather + loss partials ----------------
__global__ __launch_bounds__(256)
void refgather_kernel(const float* __restrict__ z, const float* __restrict__ cb,
                      const float* __restrict__ cnorm, const unsigned* __restrict__ top2,
                      float* __restrict__ out, float* __restrict__ partials) {
    __shared__ float zsm[32][261];
    __shared__ float crows[32][257];
    __shared__ int cand[32][16];
    __shared__ int cnt[32];
    __shared__ u64 bestk[32];
    __shared__ int sidx[32];
    __shared__ float red[256];
    __shared__ int maxc;

    const int t = threadIdx.x;
    const int bh = blockIdx.x;  // 0..1023
    const int b = bh >> 5, h = bh & 31;
    const int n0 = b * 1024 + h * 32;
    const int w = t & 31, dg = t >> 5;

    {   // stage z rows (coalesced 128B segments)
        const float* zp = z + ((size_t)b << 18) + h * 32 + w;
#pragma unroll
        for (int i = 0; i < 32; ++i) {
            int d = dg * 32 + i;
            zsm[w][d] = zp[(size_t)d * 1024];
        }
    }
    if (t < 32) cnt[t] = 0;
    if (t == 0) maxc = 0;
    __syncthreads();

    const int tk = t >> 3, l8 = t & 7;
    {   // candidate collection from per-cblk top-2
        uint2 kk = *reinterpret_cast<const uint2*>(
            top2 + ((size_t)l8 * N_TOK + (n0 + tk)) * 2);
        unsigned mn = kk.x;  // k1 <= k2
#pragma unroll
        for (int x = 1; x < 8; x <<= 1) {
            unsigned o = __shfl_xor(mn, x);
            if (o < mn) mn = o;
        }
        float thr = unpackf(mn & 0xFFFFFC00u) + MARGIN;
        float da = unpackf(kk.x & 0xFFFFFC00u);
        if (da <= thr) { int p = atomicAdd(&cnt[tk], 1); cand[tk][p] = (int)(kk.x & 1023u); }
        float db = unpackf(kk.y & 0xFFFFFC00u);
        if (db <= thr) { int p = atomicAdd(&cnt[tk], 1); cand[tk][p] = (int)(kk.y & 1023u); }
    }
    __syncthreads();
    if (t < 32) atomicMax(&maxc, cnt[t]);
    __syncthreads();

    const int mc = maxc;
    u64 best = ~0ull;
    for (int ci = 0; ci < mc; ++ci) {
        if (ci < cnt[tk]) {
            int k = cand[tk][ci];
            const float* crow = cb + (size_t)k * 256;
            float s = 0.f;
#pragma unroll
            for (int j = 0; j < 32; ++j) {
                int d = j * 8 + l8;
                s = fmaf(zsm[tk][d], crow[d], s);
            }
#pragma unroll
            for (int x = 1; x < 8; x <<= 1) s += __shfl_xor(s, x);
            float d2 = cnorm[k] - 2.f * s;
            u64 key = ((u64)packf(d2) << 32) | (unsigned)k;
            if (key < best) best = key;
        }
    }
    if (l8 == 0) bestk[tk] = best;
    __syncthreads();
    if (t < 32) {
        int k = (int)(bestk[t] & 1023ull);
        sidx[t] = k;
        out[OUT_IDX_OFF + n0 + t] = (float)k;
    }
    __syncthreads();
    {   // stage chosen codebook rows (fp32)
        const int r = t & 31, q = t >> 5;
        const float4* src = reinterpret_cast<const float4*>(cb + (size_t)sidx[r] * 256 + q * 32);
#pragma unroll
        for (int j = 0; j < 8; ++j) {
            float4 v = src[j];
            int d = q * 32 + j * 4;
            crows[r][d] = v.x; crows[r][d + 1] = v.y;
            crows[r][d + 2] = v.z; crows[r][d + 3] = v.w;
        }
    }
    __syncthreads();
    float accl = 0.f;
    float* orow = out + ((size_t)b << 18) + h * 32 + w;
#pragma unroll
    for (int i = 0; i < 32; ++i) {
        const int d = dg * 32 + i;
        const float cv = crows[w][d];
        const float zv = zsm[w][d];
        orow[(size_t)d * 1024] = cv;
        const float df = cv - zv;
        accl += df * df;
    }
    red[t] = accl;
    __syncthreads();
    for (int s = 128; s > 0; s >>= 1) {
        if (t < s) red[t] += red[t + s];
        __syncthreads();
    }
    if (t == 0) partials[bh] = red[0];
}

// ---------------- kernel 3: deterministic final loss reduction ----------------
__global__ __launch_bounds__(256) void loss_kernel(const float* __restrict__ partials,
                                                   float* __restrict__ out) {
    __shared__ float red[256];
    const int t = threadIdx.x;
    float s = partials[t] + partials[t + 256] + partials[t + 512] + partials[t + 768];
    red[t] = s;
    __syncthreads();
    for (int st = 128; st > 0; st >>= 1) {
        if (t < st) red[t] += red[t + st];
        __syncthreads();
    }
    if (t == 0) out[OUT_LOSS_OFF] = red[0] * (1.25f / (float)Z_ELEMS);
}

extern "C" void kernel_launch(void* const* d_in, const int* in_sizes, int n_in,
                              void* d_out, int out_size, void* d_ws, size_t ws_size,
                              hipStream_t stream) {
    const float* z = (const float*)d_in[0];   // [32,256,32,32] f32
    const float* cb = (const float*)d_in[1];  // [1024,256] f32
    float* out = (float*)d_out;
    float* cnorm = (float*)((char*)d_ws + WS_CNORM_OFF);
    float* partials = (float*)((char*)d_ws + WS_PART_OFF);
    unsigned char* cbf = (unsigned char*)d_ws + WS_CBF_OFF;
    unsigned* top2 = (unsigned*)((char*)d_ws + WS_TOP2_OFF);

    prep_kernel<<<16, 256, 0, stream>>>(cb, cnorm, cbf);
    screen_kernel<<<512, 256, 0, stream>>>(z, cbf, cnorm, top2);
    refgather_kernel<<<1024, 256, 0, stream>>>(z, cb, cnorm, top2, out, partials);
    loss_kernel<<<1, 256, 0, stream>>>(partials, out);
}